// Round 13
// baseline (135.635 us; speedup 1.0000x reference)
//
#include <hip/hip_runtime.h>

// GCN x2. 4 dispatches, no global atomics:
//   k_part  - deterministic slotting: block g writes bucket-b records at
//             stripe[b][g][0..96) + cnt[b][g]; per-wave LDS cursors.
//   k_sortQ - 4 blocks/bucket (512 thr): count-masked stripe read, 1024-bin
//             hist, pair-bin wave-shfl scan, sort own 256-node quarter into
//             LDS, dense writeout + rstart + mtot + dinv + y = x*dinv.
//   k_mid   - conv1 agg over sorted runs, DIRECT global reads (no staging),
//             4 thr/node; fused 4->64->relu->4 matmul; z = t*dinv,
//             out = b2 + t*dinv^2.
//   k_acc2  - conv2 agg: out[c] += dinv[c] * sum z[r].

#define CSHIFT  10
#define CNODES  1024
#define EPB     4096
#define PTH     512
#define PERBLK  96       // slots per (block,bucket); mean 41.8, +8.3 sigma
#define QPS     24       // quads per segment (PERBLK/4)
#define CAPC    18432    // dense sorted capacity per bucket (mean 16327)
#define QCAP    4608     // quarter capacity (mean 4082, +8 sigma)
#define ANODES  128
#define NBMAX   512

// deterministic-slot partition, per-wave cursors
__global__ void __launch_bounds__(PTH) k_part(
        const int* __restrict__ row, const int* __restrict__ col,
        int e, int Kc, int NB, int* __restrict__ cnt,
        unsigned* __restrict__ stripe) {
    __shared__ int wh[8][128];
    int t = threadIdx.x, w = t >> 6, bx = blockIdx.x;
    for (int k = t; k < 8 * 128; k += PTH) ((int*)wh)[k] = 0;
    __syncthreads();
    int lo = bx * EPB;
    int cbuf[8], rbuf[8];
#pragma unroll
    for (int k = 0; k < 8; ++k) {
        int i = lo + t + k * PTH;
        if (i < e) { cbuf[k] = col[i]; rbuf[k] = row[i]; }
        else { cbuf[k] = -1; rbuf[k] = 0; }
    }
#pragma unroll
    for (int k = 0; k < 8; ++k)
        if (cbuf[k] >= 0) atomicAdd(&wh[w][cbuf[k] >> CSHIFT], 1);
    __syncthreads();
    if (t < 128) {
        int s = 0;
#pragma unroll
        for (int w2 = 0; w2 < 8; ++w2) s += wh[w2][t];
        if (t < Kc) cnt[t * NB + bx] = min(s, PERBLK);
        int run = 0;
#pragma unroll
        for (int w2 = 0; w2 < 8; ++w2) { int c = wh[w2][t]; wh[w2][t] = run; run += c; }
    }
    __syncthreads();
    size_t segbase = (size_t)bx * PERBLK;
    size_t bstride = (size_t)NB * PERBLK;
#pragma unroll
    for (int k = 0; k < 8; ++k) {
        int c = cbuf[k];
        if (c < 0) continue;
        int b = c >> CSHIFT;
        int j = atomicAdd(&wh[w][b], 1);
        if (j < PERBLK)
            stripe[(size_t)b * bstride + segbase + j] =
                ((unsigned)rbuf[k] << CSHIFT) | (unsigned)(c & (CNODES - 1));
    }
}

// 4 blocks per bucket; masked stripe read x2 (L2-hit 2nd); pair-bin shfl scan
__global__ void __launch_bounds__(512) k_sortQ(
        const int* __restrict__ cnt, const unsigned* __restrict__ stripe,
        unsigned* __restrict__ sortedg, int* __restrict__ rstart,
        int* __restrict__ mtot, const float4* __restrict__ x,
        float* __restrict__ dinv, float4* __restrict__ y, int n, int NB) {
    __shared__ int hist[CNODES];
    __shared__ int scn[CNODES];
    __shared__ int cur[256];
    __shared__ int cntl[NBMAX];
    __shared__ unsigned sorted[QCAP];
    __shared__ int wsum[8];
    __shared__ int bsh[5];
    int bq = blockIdx.x, b = bq >> 2, h = bq & 3;
    int t = threadIdx.x, lane = t & 63, wv = t >> 6;
    for (int i = t; i < NB; i += 512) cntl[i] = cnt[b * NB + i];
    hist[t] = 0; hist[t + 512] = 0;
    __syncthreads();
    size_t s0 = (size_t)b * NB * PERBLK;
    int nq = (NB * PERBLK) >> 2;
    const uint4* st4 = (const uint4*)(stripe + s0);
    for (int g = t; g < nq; g += 512) {
        int seg = g / QPS;
        int j = (g - seg * QPS) << 2;
        int cb = cntl[seg];
        if (j >= cb) continue;
        uint4 wr = st4[g];
        atomicAdd(&hist[wr.x & (CNODES - 1)], 1);
        if (j + 1 < cb) atomicAdd(&hist[wr.y & (CNODES - 1)], 1);
        if (j + 2 < cb) atomicAdd(&hist[wr.z & (CNODES - 1)], 1);
        if (j + 3 < cb) atomicAdd(&hist[wr.w & (CNODES - 1)], 1);
    }
    __syncthreads();
    // pair-bin inclusive scan: thread t covers bins 2t, 2t+1
    int h0 = hist[2 * t], h1 = hist[2 * t + 1];
    int s = h0 + h1;
    int v = s;
#pragma unroll
    for (int off = 1; off < 64; off <<= 1) {
        int u = __shfl_up(v, off);
        if (lane >= off) v += u;
    }
    if (lane == 63) wsum[wv] = v;
    __syncthreads();
    int wpre = 0;
    for (int i = 0; i < wv; ++i) wpre += wsum[i];
    int incl = v + wpre;
    scn[2 * t] = incl - s;
    scn[2 * t + 1] = incl - h1;
    if (t == 0) bsh[0] = 0;
    if (t == 127) bsh[1] = incl;
    if (t == 255) bsh[2] = incl;
    if (t == 383) bsh[3] = incl;
    if (t == 511) bsh[4] = incl;
    __syncthreads();
    int m = bsh[4], base = bsh[h], qend = bsh[h + 1];
    if (t < 256) {
        int bin = (h << 8) + t;
        cur[t] = scn[bin] - base;
        rstart[(b << CSHIFT) + bin] = b * CAPC + scn[bin];
        int node = (b << CSHIFT) + bin;
        if (node < n) {
            float di = rsqrtf((float)hist[bin] + 1.0f);
            dinv[node] = di;
            float4 xv = x[node];
            y[node] = make_float4(xv.x * di, xv.y * di, xv.z * di, xv.w * di);
        }
    }
    if (h == 0 && t == 0) mtot[b] = m;
    __syncthreads();
    // place own quarter (stripe re-read, L2-hit)
    for (int g = t; g < nq; g += 512) {
        int seg = g / QPS;
        int j = (g - seg * QPS) << 2;
        int cb = cntl[seg];
        if (j >= cb) continue;
        uint4 wr = st4[g];
        int l0 = wr.x & (CNODES - 1);
        if ((l0 >> 8) == h) { int p = atomicAdd(&cur[l0 & 255], 1); if (p < QCAP) sorted[p] = wr.x >> CSHIFT; }
        if (j + 1 < cb) { int l = wr.y & (CNODES - 1);
            if ((l >> 8) == h) { int p = atomicAdd(&cur[l & 255], 1); if (p < QCAP) sorted[p] = wr.y >> CSHIFT; } }
        if (j + 2 < cb) { int l = wr.z & (CNODES - 1);
            if ((l >> 8) == h) { int p = atomicAdd(&cur[l & 255], 1); if (p < QCAP) sorted[p] = wr.z >> CSHIFT; } }
        if (j + 3 < cb) { int l = wr.w & (CNODES - 1);
            if ((l >> 8) == h) { int p = atomicAdd(&cur[l & 255], 1); if (p < QCAP) sorted[p] = wr.w >> CSHIFT; } }
    }
    __syncthreads();
    int wb = min(qend - base, QCAP);
    size_t d0 = (size_t)b * CAPC + base;
    for (int i = t; i < wb; i += 512) sortedg[d0 + i] = sorted[i];
}

// conv1 aggregation (4 thr/node, direct global run reads) + fused matmul
__global__ void __launch_bounds__(512) k_mid(
        const unsigned* __restrict__ ere, const int* __restrict__ rstart,
        const int* __restrict__ mtot, const float* __restrict__ dinv,
        const float4* __restrict__ x, const float4* __restrict__ y,
        const float* __restrict__ W1, const float* __restrict__ b1,
        const float* __restrict__ W2, const float* __restrict__ b2,
        float4* __restrict__ z, float4* __restrict__ out, int n) {
    __shared__ float4 sums[ANODES];
    int g = blockIdx.x, t = threadIdx.x;
    int nlo = g * ANODES;
    int b = nlo >> CSHIFT;
    int tt = t >> 2, q = t & 3;
    int sA = rstart[nlo + tt];
    int eA = (tt == ANODES - 1)
        ? (((g & 7) == 7) ? b * CAPC + min(mtot[b], CAPC) : rstart[nlo + ANODES])
        : rstart[nlo + tt + 1];
    float vx = 0.f, vy = 0.f, vz = 0.f, vw = 0.f;
    int i = sA + q;
    while (i + 12 < eA) {
        int r0 = ere[i], r1 = ere[i + 4], r2 = ere[i + 8], r3 = ere[i + 12];
        float4 a0 = y[r0], a1 = y[r1], a2 = y[r2], a3 = y[r3];
        vx += a0.x + a1.x + a2.x + a3.x;
        vy += a0.y + a1.y + a2.y + a3.y;
        vz += a0.z + a1.z + a2.z + a3.z;
        vw += a0.w + a1.w + a2.w + a3.w;
        i += 16;
    }
    for (; i < eA; i += 4) {
        float4 a = y[ere[i]];
        vx += a.x; vy += a.y; vz += a.z; vw += a.w;
    }
    vx += __shfl_xor(vx, 1); vx += __shfl_xor(vx, 2);
    vy += __shfl_xor(vy, 1); vy += __shfl_xor(vy, 2);
    vz += __shfl_xor(vz, 1); vz += __shfl_xor(vz, 2);
    vw += __shfl_xor(vw, 1); vw += __shfl_xor(vw, 2);
    if (q == 0) sums[tt] = make_float4(vx, vy, vz, vw);
    __syncthreads();
    int node = nlo + t;
    if (t < ANODES && node < n) {
        float di = dinv[node], sl = di * di;
        float4 sv = sums[t];
        float4 xv = x[node];
        float a0 = di * sv.x + xv.x * sl;
        float a1 = di * sv.y + xv.y * sl;
        float a2 = di * sv.z + xv.z * sl;
        float a3 = di * sv.w + xv.w * sl;
        float t0 = 0.f, t1 = 0.f, t2 = 0.f, t3 = 0.f;
#pragma unroll 8
        for (int j = 0; j < 64; ++j) {
            float hh = b1[j] + a0 * W1[j] + a1 * W1[64 + j] + a2 * W1[128 + j] + a3 * W1[192 + j];
            hh = fmaxf(hh, 0.f);
            t0 += hh * W2[j * 4 + 0];
            t1 += hh * W2[j * 4 + 1];
            t2 += hh * W2[j * 4 + 2];
            t3 += hh * W2[j * 4 + 3];
        }
        z[node] = make_float4(t0 * di, t1 * di, t2 * di, t3 * di);
        out[node] = make_float4(b2[0] + t0 * sl, b2[1] + t1 * sl,
                                b2[2] + t2 * sl, b2[3] + t3 * sl);
    }
}

__global__ void __launch_bounds__(512) k_acc2(
        const unsigned* __restrict__ ere, const int* __restrict__ rstart,
        const int* __restrict__ mtot, const float* __restrict__ dinv,
        const float4* __restrict__ z, float4* __restrict__ out, int n) {
    __shared__ float4 sums[ANODES];
    int g = blockIdx.x, t = threadIdx.x;
    int nlo = g * ANODES;
    int b = nlo >> CSHIFT;
    int tt = t >> 2, q = t & 3;
    int sA = rstart[nlo + tt];
    int eA = (tt == ANODES - 1)
        ? (((g & 7) == 7) ? b * CAPC + min(mtot[b], CAPC) : rstart[nlo + ANODES])
        : rstart[nlo + tt + 1];
    float vx = 0.f, vy = 0.f, vz = 0.f, vw = 0.f;
    int i = sA + q;
    while (i + 12 < eA) {
        int r0 = ere[i], r1 = ere[i + 4], r2 = ere[i + 8], r3 = ere[i + 12];
        float4 a0 = z[r0], a1 = z[r1], a2 = z[r2], a3 = z[r3];
        vx += a0.x + a1.x + a2.x + a3.x;
        vy += a0.y + a1.y + a2.y + a3.y;
        vz += a0.z + a1.z + a2.z + a3.z;
        vw += a0.w + a1.w + a2.w + a3.w;
        i += 16;
    }
    for (; i < eA; i += 4) {
        float4 a = z[ere[i]];
        vx += a.x; vy += a.y; vz += a.z; vw += a.w;
    }
    vx += __shfl_xor(vx, 1); vx += __shfl_xor(vx, 2);
    vy += __shfl_xor(vy, 1); vy += __shfl_xor(vy, 2);
    vz += __shfl_xor(vz, 1); vz += __shfl_xor(vz, 2);
    vw += __shfl_xor(vw, 1); vw += __shfl_xor(vw, 2);
    if (q == 0) sums[tt] = make_float4(vx, vy, vz, vw);
    __syncthreads();
    int node = nlo + t;
    if (t < ANODES && node < n) {
        float di = dinv[node];
        float4 sv = sums[t];
        float4 o = out[node];
        out[node] = make_float4(o.x + di * sv.x, o.y + di * sv.y,
                                o.z + di * sv.z, o.w + di * sv.w);
    }
}

extern "C" void kernel_launch(void* const* d_in, const int* in_sizes, int n_in,
                              void* d_out, int out_size, void* d_ws, size_t ws_size,
                              hipStream_t stream) {
    const float* x  = (const float*)d_in[0];
    const int* edge = (const int*)d_in[1];
    const float* W1 = (const float*)d_in[2];
    const float* b1 = (const float*)d_in[3];
    const float* W2 = (const float*)d_in[4];
    const float* b2 = (const float*)d_in[5];
    float* out = (float*)d_out;

    const int n = in_sizes[0] / 4;   // N nodes (S=4)
    const int e = in_sizes[1] / 2;   // E edges
    const int* row = edge;
    const int* col = edge + e;
    const int Kc = (n + CNODES - 1) >> CSHIFT;   // 98 buckets
    const int NB = (e + EPB - 1) / EPB;          // 391 partition blocks

    char* ws = (char*)d_ws;
    float* y    = (float*)ws;  ws += (size_t)4 * n * 4;
    float* zmid = (float*)ws;  ws += (size_t)4 * n * 4;
    float* dinv = (float*)ws;  ws += (size_t)n * 4;
    unsigned* stripe = (unsigned*)ws;  ws += (size_t)Kc * NB * PERBLK * 4;
    unsigned* sortedg = (unsigned*)ws; ws += (size_t)Kc * CAPC * 4;
    int* cnt    = (int*)ws;    ws += (size_t)Kc * NB * 4;
    int* rstart = (int*)ws;    ws += (size_t)Kc * CNODES * 4;
    int* mtot   = (int*)ws;    ws += (size_t)Kc * 4;

    const int ga = (n + ANODES - 1) / ANODES;    // 782

    k_part<<<NB, PTH, 0, stream>>>(row, col, e, Kc, NB, cnt, stripe);
    k_sortQ<<<4 * Kc, 512, 0, stream>>>(cnt, stripe, sortedg, rstart, mtot,
                                        (const float4*)x, dinv, (float4*)y,
                                        n, NB);
    k_mid<<<ga, 512, 0, stream>>>(sortedg, rstart, mtot, dinv, (const float4*)x,
                                  (const float4*)y, W1, b1, W2, b2,
                                  (float4*)zmid, (float4*)out, n);
    k_acc2<<<ga, 512, 0, stream>>>(sortedg, rstart, mtot, dinv,
                                   (const float4*)zmid, (float4*)out, n);
}

// Round 14
// 125.126 us; speedup vs baseline: 1.0840x; 1.0840x over previous
//
#include <hip/hip_runtime.h>

// GCN x2. 4 dispatches, no global atomics, no zero-init kernel (R12 structure,
// PERBLK 128->96):
//   k_part  - deterministic slotting: block g writes bucket-b records at
//             stripe[b][g][0..96) + cnt[b][g]. 2 syncs, no scan.
//   k_sortH - 2 blocks/bucket (1024 thr): count-masked stripe read, full
//             1024-bin hist, wave-shfl scan (3 syncs), sort own 512-node
//             half into LDS, write dense sorted + rstart + mtot + dinv +
//             y = x*dinv.
//   k_mid   - conv1 agg over sorted runs (4 thr/node, register acc, LDS-staged
//             records), fused 4->64->relu->4 matmul; writes z = t*dinv,
//             out = b2 + t*dinv^2.
//   k_acc2  - conv2 agg: out[c] += dinv[c] * sum z[r].

#define CSHIFT  10
#define CNODES  1024
#define EPB     4096
#define PTH     512
#define PERBLK  96       // slots per (block,bucket); mean 41.8, +8.3 sigma
#define CAPC    18432    // dense sorted capacity per bucket (mean 16327)
#define HCAP    9216     // half-bucket capacity (mean 8163, +11 sigma)
#define ANODES  128      // nodes per aggregation block
#define ACAP    2432     // agg staging capacity (mean 2041, +8 sigma)

// deterministic-slot partition: 1 LDS atomic + 1 store per edge, 2 syncs
__global__ void __launch_bounds__(PTH) k_part(
        const int* __restrict__ row, const int* __restrict__ col,
        int e, int Kc, int NB, int* __restrict__ cnt,
        unsigned* __restrict__ stripe) {
    __shared__ int cur[128];
    int t = threadIdx.x, bx = blockIdx.x;
    if (t < 128) cur[t] = 0;
    __syncthreads();
    int lo = bx * EPB;
    int cbuf[8], rbuf[8];
#pragma unroll
    for (int k = 0; k < 8; ++k) {
        int i = lo + t + k * PTH;
        if (i < e) { cbuf[k] = col[i]; rbuf[k] = row[i]; }
        else { cbuf[k] = -1; rbuf[k] = 0; }
    }
    size_t sbase = (size_t)bx * PERBLK;
    size_t bstride = (size_t)NB * PERBLK;
#pragma unroll
    for (int k = 0; k < 8; ++k) {
        int c = cbuf[k];
        if (c < 0) continue;
        int b = c >> CSHIFT;
        int j = atomicAdd(&cur[b], 1);
        if (j < PERBLK)
            stripe[(size_t)b * bstride + sbase + j] =
                ((unsigned)rbuf[k] << CSHIFT) | (unsigned)(c & (CNODES - 1));
    }
    __syncthreads();
    if (t < Kc) cnt[t * NB + bx] = min(cur[t], PERBLK);
}

// two blocks per bucket; masked stripe read x2 (2nd pass L2-hit);
// wave-shfl scan; own-half sort in LDS; dense writeout.
__global__ void __launch_bounds__(1024) k_sortH(
        const int* __restrict__ cnt, const unsigned* __restrict__ stripe,
        unsigned* __restrict__ sortedg, int* __restrict__ rstart,
        int* __restrict__ mtot, const float4* __restrict__ x,
        float* __restrict__ dinv, float4* __restrict__ y, int n, int NB) {
    __shared__ int hist[CNODES];
    __shared__ int cur[512];
    __shared__ int cntl[512];        // NB <= 512
    __shared__ unsigned sorted[HCAP];
    __shared__ int wsum[16], wpre[16];
    __shared__ int lowsh, msh;
    int bh = blockIdx.x, b = bh >> 1, h = bh & 1;
    int t = threadIdx.x, lane = t & 63, wv = t >> 6;
    for (int i = t; i < NB; i += 1024) cntl[i] = cnt[b * NB + i];
    hist[t] = 0;
    __syncthreads();
    size_t s0 = (size_t)b * NB * PERBLK;
    int nslot4 = (NB * PERBLK) >> 2;
    const uint4* st4 = (const uint4*)(stripe + s0);
    for (int g = t; g < nslot4; g += 1024) {
        int slot = g << 2;
        int seg = slot / PERBLK;
        int j = slot - seg * PERBLK;
        int cb = cntl[seg];
        if (j >= cb) continue;               // whole quad invalid
        uint4 w = st4[g];
        atomicAdd(&hist[w.x & (CNODES - 1)], 1);
        if (j + 1 < cb) atomicAdd(&hist[w.y & (CNODES - 1)], 1);
        if (j + 2 < cb) atomicAdd(&hist[w.z & (CNODES - 1)], 1);
        if (j + 3 < cb) atomicAdd(&hist[w.w & (CNODES - 1)], 1);
    }
    __syncthreads();
    // wave-shfl inclusive scan over 1024 bins (3 syncs)
    int hv = hist[t];
    int v = hv;
#pragma unroll
    for (int off = 1; off < 64; off <<= 1) {
        int u = __shfl_up(v, off);
        if (lane >= off) v += u;
    }
    if (lane == 63) wsum[wv] = v;
    __syncthreads();
    if (t < 16) {
        int s = 0;
        for (int i = 0; i < t; ++i) s += wsum[i];
        wpre[t] = s;
    }
    __syncthreads();
    int incl = v + wpre[wv];
    if (t == 511) lowsh = incl;
    if (t == 1023) msh = incl;
    __syncthreads();
    int st = incl - hv;
    int low = lowsh, m = msh;
    int base = h ? low : 0;
    if ((t >> 9) == h) {
        cur[t & 511] = st - base;
        rstart[(b << CSHIFT) + t] = b * CAPC + st;
        int node = (b << CSHIFT) + t;
        if (node < n) {
            float di = rsqrtf((float)hv + 1.0f);
            dinv[node] = di;
            float4 xv = x[node];
            y[node] = make_float4(xv.x * di, xv.y * di, xv.z * di, xv.w * di);
        }
    }
    if (t == 0 && h == 0) mtot[b] = m;
    __syncthreads();
    // place own half (stripe re-read, L2-hit)
    for (int g = t; g < nslot4; g += 1024) {
        int slot = g << 2;
        int seg = slot / PERBLK;
        int j = slot - seg * PERBLK;
        int cb = cntl[seg];
        if (j >= cb) continue;
        uint4 w = st4[g];
        int l0 = w.x & (CNODES - 1);
        if ((l0 >> 9) == h) { int p = atomicAdd(&cur[l0 & 511], 1); if (p < HCAP) sorted[p] = w.x >> CSHIFT; }
        if (j + 1 < cb) { int l = w.y & (CNODES - 1);
            if ((l >> 9) == h) { int p = atomicAdd(&cur[l & 511], 1); if (p < HCAP) sorted[p] = w.y >> CSHIFT; } }
        if (j + 2 < cb) { int l = w.z & (CNODES - 1);
            if ((l >> 9) == h) { int p = atomicAdd(&cur[l & 511], 1); if (p < HCAP) sorted[p] = w.z >> CSHIFT; } }
        if (j + 3 < cb) { int l = w.w & (CNODES - 1);
            if ((l >> 9) == h) { int p = atomicAdd(&cur[l & 511], 1); if (p < HCAP) sorted[p] = w.w >> CSHIFT; } }
    }
    __syncthreads();
    int cown = h ? (m - low) : low;
    int wb = min(cown, HCAP);
    size_t d0 = (size_t)b * CAPC + base;
    for (int i = t; i < wb; i += 1024) sortedg[d0 + i] = sorted[i];
}

// conv1 aggregation (4 threads/node, LDS-staged records) + fused node matmul
__global__ void __launch_bounds__(512) k_mid(
        const unsigned* __restrict__ ere, const int* __restrict__ rstart,
        const int* __restrict__ mtot, const float* __restrict__ dinv,
        const float4* __restrict__ x, const float4* __restrict__ y,
        const float* __restrict__ W1, const float* __restrict__ b1,
        const float* __restrict__ W2, const float* __restrict__ b2,
        float4* __restrict__ z, float4* __restrict__ out, int n) {
    __shared__ unsigned recs[ACAP];
    __shared__ float4 sums[ANODES];
    int g = blockIdx.x, t = threadIdx.x;
    int nlo = g * ANODES;
    int b = nlo >> CSHIFT;
    int s0 = rstart[nlo];
    int e0 = ((g & 7) == 7) ? b * CAPC + min(mtot[b], CAPC)
                            : rstart[nlo + ANODES];
    int len = min(e0 - s0, ACAP);
    for (int i = t; i < len; i += 512) recs[i] = ere[s0 + i];
    __syncthreads();
    int tt = t >> 2, q = t & 3;
    int s = rstart[nlo + tt] - s0;
    int epos = (tt == ANODES - 1) ? len : min(rstart[nlo + tt + 1] - s0, len);
    float vx = 0.f, vy = 0.f, vz = 0.f, vw = 0.f;
    int i = s + q;
    while (i + 12 < epos) {
        int r0 = recs[i], r1 = recs[i + 4], r2 = recs[i + 8], r3 = recs[i + 12];
        float4 a0 = y[r0], a1 = y[r1], a2 = y[r2], a3 = y[r3];
        vx += a0.x + a1.x + a2.x + a3.x;
        vy += a0.y + a1.y + a2.y + a3.y;
        vz += a0.z + a1.z + a2.z + a3.z;
        vw += a0.w + a1.w + a2.w + a3.w;
        i += 16;
    }
    for (; i < epos; i += 4) {
        float4 a = y[recs[i]];
        vx += a.x; vy += a.y; vz += a.z; vw += a.w;
    }
    vx += __shfl_xor(vx, 1); vx += __shfl_xor(vx, 2);
    vy += __shfl_xor(vy, 1); vy += __shfl_xor(vy, 2);
    vz += __shfl_xor(vz, 1); vz += __shfl_xor(vz, 2);
    vw += __shfl_xor(vw, 1); vw += __shfl_xor(vw, 2);
    if (q == 0) sums[tt] = make_float4(vx, vy, vz, vw);
    __syncthreads();
    int node = nlo + t;
    if (t < ANODES && node < n) {
        float di = dinv[node], sl = di * di;
        float4 sv = sums[t];
        float4 xv = x[node];
        float a0 = di * sv.x + xv.x * sl;
        float a1 = di * sv.y + xv.y * sl;
        float a2 = di * sv.z + xv.z * sl;
        float a3 = di * sv.w + xv.w * sl;
        float t0 = 0.f, t1 = 0.f, t2 = 0.f, t3 = 0.f;
#pragma unroll 8
        for (int j = 0; j < 64; ++j) {
            float hh = b1[j] + a0 * W1[j] + a1 * W1[64 + j] + a2 * W1[128 + j] + a3 * W1[192 + j];
            hh = fmaxf(hh, 0.f);
            t0 += hh * W2[j * 4 + 0];
            t1 += hh * W2[j * 4 + 1];
            t2 += hh * W2[j * 4 + 2];
            t3 += hh * W2[j * 4 + 3];
        }
        z[node] = make_float4(t0 * di, t1 * di, t2 * di, t3 * di);
        out[node] = make_float4(b2[0] + t0 * sl, b2[1] + t1 * sl,
                                b2[2] + t2 * sl, b2[3] + t3 * sl);
    }
}

__global__ void __launch_bounds__(512) k_acc2(
        const unsigned* __restrict__ ere, const int* __restrict__ rstart,
        const int* __restrict__ mtot, const float* __restrict__ dinv,
        const float4* __restrict__ z, float4* __restrict__ out, int n) {
    __shared__ unsigned recs[ACAP];
    __shared__ float4 sums[ANODES];
    int g = blockIdx.x, t = threadIdx.x;
    int nlo = g * ANODES;
    int b = nlo >> CSHIFT;
    int s0 = rstart[nlo];
    int e0 = ((g & 7) == 7) ? b * CAPC + min(mtot[b], CAPC)
                            : rstart[nlo + ANODES];
    int len = min(e0 - s0, ACAP);
    for (int i = t; i < len; i += 512) recs[i] = ere[s0 + i];
    __syncthreads();
    int tt = t >> 2, q = t & 3;
    int s = rstart[nlo + tt] - s0;
    int epos = (tt == ANODES - 1) ? len : min(rstart[nlo + tt + 1] - s0, len);
    float vx = 0.f, vy = 0.f, vz = 0.f, vw = 0.f;
    int i = s + q;
    while (i + 12 < epos) {
        int r0 = recs[i], r1 = recs[i + 4], r2 = recs[i + 8], r3 = recs[i + 12];
        float4 a0 = z[r0], a1 = z[r1], a2 = z[r2], a3 = z[r3];
        vx += a0.x + a1.x + a2.x + a3.x;
        vy += a0.y + a1.y + a2.y + a3.y;
        vz += a0.z + a1.z + a2.z + a3.z;
        vw += a0.w + a1.w + a2.w + a3.w;
        i += 16;
    }
    for (; i < epos; i += 4) {
        float4 a = z[recs[i]];
        vx += a.x; vy += a.y; vz += a.z; vw += a.w;
    }
    vx += __shfl_xor(vx, 1); vx += __shfl_xor(vx, 2);
    vy += __shfl_xor(vy, 1); vy += __shfl_xor(vy, 2);
    vz += __shfl_xor(vz, 1); vz += __shfl_xor(vz, 2);
    vw += __shfl_xor(vw, 1); vw += __shfl_xor(vw, 2);
    if (q == 0) sums[tt] = make_float4(vx, vy, vz, vw);
    __syncthreads();
    int node = nlo + t;
    if (t < ANODES && node < n) {
        float di = dinv[node];
        float4 sv = sums[t];
        float4 o = out[node];
        out[node] = make_float4(o.x + di * sv.x, o.y + di * sv.y,
                                o.z + di * sv.z, o.w + di * sv.w);
    }
}

extern "C" void kernel_launch(void* const* d_in, const int* in_sizes, int n_in,
                              void* d_out, int out_size, void* d_ws, size_t ws_size,
                              hipStream_t stream) {
    const float* x  = (const float*)d_in[0];
    const int* edge = (const int*)d_in[1];
    const float* W1 = (const float*)d_in[2];
    const float* b1 = (const float*)d_in[3];
    const float* W2 = (const float*)d_in[4];
    const float* b2 = (const float*)d_in[5];
    float* out = (float*)d_out;

    const int n = in_sizes[0] / 4;   // N nodes (S=4)
    const int e = in_sizes[1] / 2;   // E edges
    const int* row = edge;
    const int* col = edge + e;
    const int Kc = (n + CNODES - 1) >> CSHIFT;   // 98 buckets
    const int NB = (e + EPB - 1) / EPB;          // 391 partition blocks

    char* ws = (char*)d_ws;
    float* y    = (float*)ws;  ws += (size_t)4 * n * 4;
    float* zmid = (float*)ws;  ws += (size_t)4 * n * 4;
    float* dinv = (float*)ws;  ws += (size_t)n * 4;
    unsigned* stripe = (unsigned*)ws;  ws += (size_t)Kc * NB * PERBLK * 4;
    unsigned* sortedg = (unsigned*)ws; ws += (size_t)Kc * CAPC * 4;
    int* cnt    = (int*)ws;    ws += (size_t)Kc * NB * 4;
    int* rstart = (int*)ws;    ws += (size_t)Kc * CNODES * 4;
    int* mtot   = (int*)ws;    ws += (size_t)Kc * 4;

    const int ga = (n + ANODES - 1) / ANODES;    // 782

    k_part<<<NB, PTH, 0, stream>>>(row, col, e, Kc, NB, cnt, stripe);
    k_sortH<<<2 * Kc, 1024, 0, stream>>>(cnt, stripe, sortedg, rstart, mtot,
                                         (const float4*)x, dinv, (float4*)y,
                                         n, NB);
    k_mid<<<ga, 512, 0, stream>>>(sortedg, rstart, mtot, dinv, (const float4*)x,
                                  (const float4*)y, W1, b1, W2, b2,
                                  (float4*)zmid, (float4*)out, n);
    k_acc2<<<ga, 512, 0, stream>>>(sortedg, rstart, mtot, dinv,
                                   (const float4*)zmid, (float4*)out, n);
}